// Round 9
// baseline (520.801 us; speedup 1.0000x reference)
//
#include <hip/hip_runtime.h>
#include <hip/hip_fp16.h>
#include <hip/hip_cooperative_groups.h>

namespace cg = cooperative_groups;

#define N_NODES 50000
#define N_EDGES 800000
#define N_GRAPHS 64

#define CAP 64            // fixed-stride CSR row capacity; P(deg>=64) ~ 1e-13 on Poisson(16)
#define BUILD_BLOCKS 1024 // coop build grid: 8 ranges x 128 stripes
#define TAIL_BLOCKS 1024  // coop tail grid: 4 blocks/CU (LDS-limited)

struct __align__(8)  h4v { __half2 a, b; };          // 4 fp16 = 8 B
struct __align__(16) h8v { __half2 a, b, c, d; };    // 8 fp16 = 16 B (gather unit)

// ---------------- coop kernel 1: zero+gend+W2cast -> grid.sync -> XCD-partitioned fill ----------------
// R8 lesson: per-dispatch overhead (~10-15us) dominates this pipeline -> fuse via grid sync.
// pk[] dropped: fill reads dst (and src only when in-range) straight from L2/L3.

__global__ __launch_bounds__(256, 4) void k_build(
    const int* __restrict__ src, const int* __restrict__ dst,
    int* __restrict__ cnt, float* __restrict__ sums,
    const float* __restrict__ W2, __half* __restrict__ w2h,
    const int* __restrict__ batch, int* __restrict__ gend,
    unsigned short* __restrict__ csr) {
    const int tid = blockIdx.x * 256 + threadIdx.x;
    // ---- phase 0: init ----
    if (tid < N_NODES) {
        cnt[tid] = 0;
        // sorted batch: boundary -> this node ends its graph (all 64 graphs populated)
        if (tid == N_NODES - 1 || batch[tid] != batch[tid + 1]) gend[batch[tid]] = tid + 1;
    }
    if (tid < N_GRAPHS * 128) sums[tid] = 0.f;
    if (tid < 64 * 128) w2h[tid] = __float2half_rn(W2[tid]);

    cg::this_grid().sync();

    // ---- phase 1: one-pass fixed-stride CSR fill, XCD-partitioned ----
    const int range = blockIdx.x & 7;
    const int stripe = blockIdx.x >> 3;              // 0..127
    const int lo = range * (N_NODES / 8);
    const int hi = lo + (N_NODES / 8);
    for (int e = stripe * 256 + threadIdx.x; e < N_EDGES; e += (BUILD_BLOCKS / 8) * 256) {
        int d = dst[e];
        if (d >= lo && d < hi) {
            int slot = atomicAdd(&cnt[d], 1);
            if (slot < CAP) csr[(size_t)d * CAP + slot] = (unsigned short)src[e];
        }
    }
}

// ---------------- GEMM1: g̃(fp16) = dinv ⊙ (x @ W1) ----------------
// dinv computed on the fly from cnt (rsqrt of degree+1).

__global__ __launch_bounds__(256) void k_gemm1(const float* __restrict__ A,
                                               const float* __restrict__ W,
                                               const int* __restrict__ cnt,
                                               __half* __restrict__ Cout, int N) {
    const int FIN = 128;
    __shared__ __align__(16) float As[64 * (FIN + 2)];
    __shared__ __align__(16) float Wsm[FIN * 64];
    const int t = threadIdx.x;
    const int row0 = blockIdx.x * 64;

    const int NF4 = 64 * FIN / 4;
    for (int idx = t; idx < NF4; idx += 256) {
        int r = idx / (FIN / 4);
        int c4 = idx % (FIN / 4);
        float4 v = make_float4(0.f, 0.f, 0.f, 0.f);
        if (row0 + r < N) v = ((const float4*)(A + (size_t)(row0 + r) * FIN))[c4];
        float* p = &As[r * (FIN + 2) + c4 * 4];
        ((float2*)p)[0] = make_float2(v.x, v.y);
        ((float2*)p)[1] = make_float2(v.z, v.w);
    }
    for (int idx = t; idx < FIN * 16; idx += 256) {
        int r = idx / 16, c4 = idx % 16;
        *((float4*)&Wsm[r * 64 + c4 * 4]) = ((const float4*)(W + (size_t)r * 64))[c4];
    }
    __syncthreads();

    const int tc = (t & 15) * 4;
    const int tr = (t >> 4) * 4;
    float acc[4][4] = {};
#pragma unroll 4
    for (int k = 0; k < FIN; k += 2) {
        float2 a[4];
#pragma unroll
        for (int r = 0; r < 4; ++r)
            a[r] = *(const float2*)&As[(tr + r) * (FIN + 2) + k];
        float4 w0 = *(const float4*)&Wsm[k * 64 + tc];
        float4 w1 = *(const float4*)&Wsm[(k + 1) * 64 + tc];
#pragma unroll
        for (int r = 0; r < 4; ++r) {
            acc[r][0] = fmaf(a[r].x, w0.x, acc[r][0]);
            acc[r][1] = fmaf(a[r].x, w0.y, acc[r][1]);
            acc[r][2] = fmaf(a[r].x, w0.z, acc[r][2]);
            acc[r][3] = fmaf(a[r].x, w0.w, acc[r][3]);
            acc[r][0] = fmaf(a[r].y, w1.x, acc[r][0]);
            acc[r][1] = fmaf(a[r].y, w1.y, acc[r][1]);
            acc[r][2] = fmaf(a[r].y, w1.z, acc[r][2]);
            acc[r][3] = fmaf(a[r].y, w1.w, acc[r][3]);
        }
    }

#pragma unroll
    for (int r = 0; r < 4; ++r) {
        int row = row0 + tr + r;
        if (row < N) {
            float s = rsqrtf((float)(min(cnt[row], CAP) + 1));
            __half2* dsth = (__half2*)(Cout + (size_t)row * 64 + tc);
            dsth[0] = __floats2half2_rn(acc[r][0] * s, acc[r][1] * s);
            dsth[1] = __floats2half2_rn(acc[r][2] * s, acc[r][3] * s);
        }
    }
}

// ---------------- gather core: 8 lanes/node, 16B/lane (R8 shape) ----------------

__device__ __forceinline__ void gather_node(const h8v* __restrict__ h,
                                            const unsigned short* __restrict__ row,
                                            int c, int lane,
                                            float* f /*8 sums incl self*/) {
    float g0 = 0, g1 = 0, g2 = 0, g3 = 0, g4 = 0, g5 = 0, g6 = 0, g7 = 0;
    int j = 0;
    for (; j + 4 <= c; j += 4) {
        ushort4 s4 = *(const ushort4*)(row + j);
        h8v v0 = h[(size_t)s4.x * 8 + lane];
        h8v v1 = h[(size_t)s4.y * 8 + lane];
        h8v v2 = h[(size_t)s4.z * 8 + lane];
        h8v v3 = h[(size_t)s4.w * 8 + lane];
        float2 a0 = __half22float2(v0.a), a1 = __half22float2(v0.b),
               a2 = __half22float2(v0.c), a3 = __half22float2(v0.d);
        float2 b0 = __half22float2(v1.a), b1 = __half22float2(v1.b),
               b2 = __half22float2(v1.c), b3 = __half22float2(v1.d);
        f[0] += a0.x; f[1] += a0.y; f[2] += a1.x; f[3] += a1.y;
        f[4] += a2.x; f[5] += a2.y; f[6] += a3.x; f[7] += a3.y;
        g0 += b0.x; g1 += b0.y; g2 += b1.x; g3 += b1.y;
        g4 += b2.x; g5 += b2.y; g6 += b3.x; g7 += b3.y;
        float2 c0 = __half22float2(v2.a), c1 = __half22float2(v2.b),
               c2 = __half22float2(v2.c), c3 = __half22float2(v2.d);
        float2 d0 = __half22float2(v3.a), d1 = __half22float2(v3.b),
               d2 = __half22float2(v3.c), d3 = __half22float2(v3.d);
        f[0] += c0.x; f[1] += c0.y; f[2] += c1.x; f[3] += c1.y;
        f[4] += c2.x; f[5] += c2.y; f[6] += c3.x; f[7] += c3.y;
        g0 += d0.x; g1 += d0.y; g2 += d1.x; g3 += d1.y;
        g4 += d2.x; g5 += d2.y; g6 += d3.x; g7 += d3.y;
    }
    for (; j < c; ++j) {
        h8v v = h[(size_t)row[j] * 8 + lane];
        float2 a0 = __half22float2(v.a), a1 = __half22float2(v.b),
               a2 = __half22float2(v.c), a3 = __half22float2(v.d);
        f[0] += a0.x; f[1] += a0.y; f[2] += a1.x; f[3] += a1.y;
        f[4] += a2.x; f[5] += a2.y; f[6] += a3.x; f[7] += a3.y;
    }
    f[0] += g0; f[1] += g1; f[2] += g2; f[3] += g3;
    f[4] += g4; f[5] += g5; f[6] += g6; f[7] += g7;
}

// ---------------- conv1 aggregate (standalone, max occupancy — R2 lesson) ----------------

__global__ void k_agg1(const h8v* __restrict__ h, const int* __restrict__ cnt,
                       const unsigned short* __restrict__ csr,
                       const float* __restrict__ bias, h8v* __restrict__ out, int N) {
    int node = blockIdx.x * 32 + (threadIdx.x >> 3);
    int lane = threadIdx.x & 7;
    if (node >= N) return;
    int c = min(cnt[node], CAP);
    float di = rsqrtf((float)(c + 1));
    h8v sv = h[(size_t)node * 8 + lane];  // self loop (pre-scaled)
    float2 p0 = __half22float2(sv.a), p1 = __half22float2(sv.b);
    float2 p2 = __half22float2(sv.c), p3 = __half22float2(sv.d);
    float f[8] = {p0.x, p0.y, p1.x, p1.y, p2.x, p2.y, p3.x, p3.y};
    gather_node(h, csr + (size_t)node * CAP, c, lane, f);
    float4 bv0 = ((const float4*)bias)[lane * 2];
    float4 bv1 = ((const float4*)bias)[lane * 2 + 1];
    float r0 = fmaf(f[0], di, bv0.x); r0 = r0 > 0.f ? r0 : 0.f;
    float r1 = fmaf(f[1], di, bv0.y); r1 = r1 > 0.f ? r1 : 0.f;
    float r2 = fmaf(f[2], di, bv0.z); r2 = r2 > 0.f ? r2 : 0.f;
    float r3 = fmaf(f[3], di, bv0.w); r3 = r3 > 0.f ? r3 : 0.f;
    float r4 = fmaf(f[4], di, bv1.x); r4 = r4 > 0.f ? r4 : 0.f;
    float r5 = fmaf(f[5], di, bv1.y); r5 = r5 > 0.f ? r5 : 0.f;
    float r6 = fmaf(f[6], di, bv1.z); r6 = r6 > 0.f ? r6 : 0.f;
    float r7 = fmaf(f[7], di, bv1.w); r7 = r7 > 0.f ? r7 : 0.f;
    h8v o;
    o.a = __floats2half2_rn(di * r0, di * r1);
    o.b = __floats2half2_rn(di * r2, di * r3);
    o.c = __floats2half2_rn(di * r4, di * r5);
    o.d = __floats2half2_rn(di * r6, di * r7);
    out[(size_t)node * 8 + lane] = o;
}

// ---------------- coop kernel 2: agg2 -> sync -> gemm_pool128 -> sync -> MLP ----------------
// Replaces 3 dispatches with 1 (+2 grid syncs).

__global__ __launch_bounds__(256, 4) void k_tail(
    const h8v* __restrict__ hB,        // h̃1
    const int* __restrict__ cnt,
    const unsigned short* __restrict__ csr,
    h8v* __restrict__ zA,              // z̃ out (= bufA)
    const __half2* __restrict__ w2h,   // [64][64] half2
    const float* __restrict__ b2,      // bias[128]
    const int* __restrict__ batch,
    float* __restrict__ sums,
    const int* __restrict__ gend,
    const float* __restrict__ M1, const float* __restrict__ c1,
    const float* __restrict__ M2, const float* __restrict__ c2,
    const float* __restrict__ M3, const float* __restrict__ c3,
    const float* __restrict__ M4, const float* __restrict__ c4,
    float* __restrict__ out) {
    __shared__ __align__(16) float As[64 * 66];     // 16.9 KB
    __shared__ __align__(16) __half2 Wh[64 * 64];   // 16 KB
    __shared__ float red[8][132];                   // 4.2 KB
    __shared__ int batchLDS[64];
    __shared__ float gv[128], t1[64], t2[64], t3[64];
    __shared__ float cntb;
    const int t = threadIdx.x;
    const int N = N_NODES;

    // ---- phase A: conv2 aggregate z̃ = dinv ⊙ (Σ h̃1), grid-stride ----
    {
        const int lane = t & 7;
        const int grp = t >> 3;    // 0..31
        for (int base = blockIdx.x * 32; base < N; base += TAIL_BLOCKS * 32) {
            int node = base + grp;
            if (node < N) {
                int c = min(cnt[node], CAP);
                float di = rsqrtf((float)(c + 1));
                h8v sv = hB[(size_t)node * 8 + lane];
                float2 p0 = __half22float2(sv.a), p1 = __half22float2(sv.b);
                float2 p2 = __half22float2(sv.c), p3 = __half22float2(sv.d);
                float f[8] = {p0.x, p0.y, p1.x, p1.y, p2.x, p2.y, p3.x, p3.y};
                gather_node(hB, csr + (size_t)node * CAP, c, lane, f);
                h8v o;
                o.a = __floats2half2_rn(f[0] * di, f[1] * di);
                o.b = __floats2half2_rn(f[2] * di, f[3] * di);
                o.c = __floats2half2_rn(f[4] * di, f[5] * di);
                o.d = __floats2half2_rn(f[6] * di, f[7] * di);
                zA[(size_t)node * 8 + lane] = o;
            }
        }
    }

    cg::this_grid().sync();

    // ---- phase B: GEMM2 + bias + relu + per-graph pooled atomics, grid-stride tiles ----
    const __half2* A2 = (const __half2*)zA;
    for (int row0 = blockIdx.x * 64; row0 < N; row0 += TAIL_BLOCKS * 64) {
        for (int idx = t; idx < 4096; idx += 256) Wh[idx] = w2h[idx];
        if (t < 64) batchLDS[t] = batch[min(row0 + t, N - 1)];
        for (int idx = t; idx < 64 * 32; idx += 256) {
            int r = idx >> 5, c2 = idx & 31;
            float2 v = make_float2(0.f, 0.f);
            if (row0 + r < N) v = __half22float2(A2[(size_t)(row0 + r) * 32 + c2]);
            *(float2*)&As[r * 66 + c2 * 2] = v;
        }
        __syncthreads();

        const int tc = (t & 31) * 4;   // 0..124
        const int tr = (t >> 5) * 8;   // 0..56
        float acc[8][4] = {};
#pragma unroll 4
        for (int k = 0; k < 64; k += 2) {
            float2 a[8];
#pragma unroll
            for (int r = 0; r < 8; ++r)
                a[r] = *(const float2*)&As[(tr + r) * 66 + k];
            h4v wv0 = *(const h4v*)&Wh[k * 64 + (tc >> 1)];
            h4v wv1 = *(const h4v*)&Wh[(k + 1) * 64 + (tc >> 1)];
            float2 w00 = __half22float2(wv0.a), w01 = __half22float2(wv0.b);
            float2 w10 = __half22float2(wv1.a), w11 = __half22float2(wv1.b);
#pragma unroll
            for (int r = 0; r < 8; ++r) {
                acc[r][0] = fmaf(a[r].x, w00.x, acc[r][0]);
                acc[r][1] = fmaf(a[r].x, w00.y, acc[r][1]);
                acc[r][2] = fmaf(a[r].x, w01.x, acc[r][2]);
                acc[r][3] = fmaf(a[r].x, w01.y, acc[r][3]);
                acc[r][0] = fmaf(a[r].y, w10.x, acc[r][0]);
                acc[r][1] = fmaf(a[r].y, w10.y, acc[r][1]);
                acc[r][2] = fmaf(a[r].y, w11.x, acc[r][2]);
                acc[r][3] = fmaf(a[r].y, w11.y, acc[r][3]);
            }
        }

        float4 bv = *(const float4*)&b2[tc];
        float v[8][4];
#pragma unroll
        for (int r = 0; r < 8; ++r) {
            bool valid = (row0 + tr + r) < N;
            v[r][0] = valid ? fmaxf(acc[r][0] + bv.x, 0.f) : 0.f;
            v[r][1] = valid ? fmaxf(acc[r][1] + bv.y, 0.f) : 0.f;
            v[r][2] = valid ? fmaxf(acc[r][2] + bv.z, 0.f) : 0.f;
            v[r][3] = valid ? fmaxf(acc[r][3] + bv.w, 0.f) : 0.f;
        }

        const int g0 = batchLDS[0], g1 = batchLDS[63];
        const int rg = t >> 5;
        for (int g = g0; g <= g1; ++g) {
            float p0 = 0.f, p1 = 0.f, p2 = 0.f, p3 = 0.f;
#pragma unroll
            for (int r = 0; r < 8; ++r) {
                if (batchLDS[tr + r] == g) { p0 += v[r][0]; p1 += v[r][1]; p2 += v[r][2]; p3 += v[r][3]; }
            }
            red[rg][tc + 0] = p0; red[rg][tc + 1] = p1;
            red[rg][tc + 2] = p2; red[rg][tc + 3] = p3;
            __syncthreads();
            for (int off = 4; off > 0; off >>= 1) {
                if (rg < off) {
#pragma unroll
                    for (int c = 0; c < 4; ++c) red[rg][tc + c] += red[rg + off][tc + c];
                }
                __syncthreads();
            }
            if (rg == 0) {
#pragma unroll
                for (int c = 0; c < 4; ++c)
                    atomicAdd(&sums[g * 128 + tc + c], red[0][tc + c]);
            }
            __syncthreads();
        }
        __syncthreads();
    }

    cg::this_grid().sync();

    // ---- phase C: MLP head, blocks 0..63 ----
    if (blockIdx.x < N_GRAPHS) {
        int b = blockIdx.x;
        if (t == 0) {
            int lb = (b > 0) ? gend[b - 1] : 0;
            cntb = fmaxf((float)(gend[b] - lb), 1.0f);
        }
        __syncthreads();
        if (t < 128) gv[t] = sums[b * 128 + t] / cntb;
        __syncthreads();
        if (t < 64) {
            float acc = c1[t];
            for (int k = 0; k < 128; ++k) acc = fmaf(gv[k], M1[k * 64 + t], acc);
            t1[t] = acc >= 0.f ? acc : 0.2f * acc;
        }
        __syncthreads();
        if (t < 64) {
            float acc = c2[t];
            for (int k = 0; k < 64; ++k) acc = fmaf(t1[k], M2[k * 64 + t], acc);
            t2[t] = acc >= 0.f ? acc : 0.1f * acc;
        }
        __syncthreads();
        if (t < 64) {
            float acc = c3[t];
            for (int k = 0; k < 64; ++k) acc = fmaf(t2[k], M3[k * 64 + t], acc);
            t3[t] = acc >= 0.f ? acc : 0.1f * acc;
        }
        __syncthreads();
        if (t == 0) {
            float acc = c4[0];
            for (int k = 0; k < 64; ++k) acc = fmaf(t3[k], M4[k], acc);
            out[b] = fmaxf(acc, 0.f);
        }
    }
}

// ---------------- launch ----------------

extern "C" void kernel_launch(void* const* d_in, const int* in_sizes, int n_in,
                              void* d_out, int out_size, void* d_ws, size_t ws_size,
                              hipStream_t stream) {
    const float* x   = (const float*)d_in[0];
    const int*   ei  = (const int*)d_in[1];
    const int*   bat = (const int*)d_in[2];
    const float* W1  = (const float*)d_in[3];
    const float* b1  = (const float*)d_in[4];
    const float* W2  = (const float*)d_in[5];
    const float* b2  = (const float*)d_in[6];
    const float* M1  = (const float*)d_in[7];
    const float* c1  = (const float*)d_in[8];
    const float* M2  = (const float*)d_in[9];
    const float* c2  = (const float*)d_in[10];
    const float* M3  = (const float*)d_in[11];
    const float* c3  = (const float*)d_in[12];
    const float* M4  = (const float*)d_in[13];
    const float* c4  = (const float*)d_in[14];
    float* out = (float*)d_out;

    const int* src = ei;            // edge_index[0]
    const int* dst = ei + N_EDGES;  // edge_index[1]

    // workspace layout
    float* bufA    = (float*)d_ws;                          // g̃ / z̃: N*64 fp16
    float* bufB    = bufA + (size_t)N_NODES * 64;           // h̃1: N*64 fp16
    float* sums    = bufB + (size_t)N_NODES * 64;           // 64*128 f
    int*   cnt     = (int*)(sums + N_GRAPHS * 128);         // N i (degree/slot counter)
    unsigned short* csr = (unsigned short*)(cnt + N_NODES); // N*CAP u16 (fixed-stride rows)
    __half* w2h    = (__half*)(csr + (size_t)N_NODES * CAP);// 64*128 fp16
    int*   gend    = (int*)(w2h + 64 * 128);                // 64 i (graph end indices)

    // ---- coop build: init + one-pass CSR fill (was 2 dispatches) ----
    {
        void* args[] = {(void*)&src, (void*)&dst, (void*)&cnt, (void*)&sums,
                        (void*)&W2, (void*)&w2h, (void*)&bat, (void*)&gend, (void*)&csr};
        hipLaunchCooperativeKernel((const void*)k_build, dim3(BUILD_BLOCKS), dim3(256),
                                   args, 0, stream);
    }

    const int NBLK = (N_NODES + 63) / 64;   // 782
    const int ABLK = (N_NODES + 31) / 32;   // 1563

    // ---- conv1: g̃(fp16) = dinv ⊙ (x@W1); h̃1(fp16) = dinv ⊙ relu(Â-sum + b1) ----
    k_gemm1<<<NBLK, 256, 0, stream>>>(x, W1, cnt, (__half*)bufA, N_NODES);
    k_agg1<<<ABLK, 256, 0, stream>>>(
        (const h8v*)bufA, cnt, csr, b1, (h8v*)bufB, N_NODES);

    // ---- coop tail: agg2 -> gemm_pool -> mlp (was 3 dispatches) ----
    {
        const h8v* hB = (const h8v*)bufB;
        h8v* zA = (h8v*)bufA;
        const __half2* w2h2 = (const __half2*)w2h;
        void* args[] = {(void*)&hB, (void*)&cnt, (void*)&csr, (void*)&zA, (void*)&w2h2,
                        (void*)&b2, (void*)&bat, (void*)&sums, (void*)&gend,
                        (void*)&M1, (void*)&c1, (void*)&M2, (void*)&c2,
                        (void*)&M3, (void*)&c3, (void*)&M4, (void*)&c4, (void*)&out};
        hipLaunchCooperativeKernel((const void*)k_tail, dim3(TAIL_BLOCKS), dim3(256),
                                   args, 0, stream);
    }
}

// Round 11
// 287.452 us; speedup vs baseline: 1.8118x; 1.8118x over previous
//
#include <hip/hip_runtime.h>
#include <hip/hip_fp16.h>

#define N_NODES 50000
#define N_EDGES 800000
#define N_GRAPHS 64

#define CAP 64            // fixed-stride CSR row capacity; P(deg>=64) ~ 1e-13 on Poisson(16)
#define FILL_STRIPES 256  // blocks per node-range; grid = 8*FILL_STRIPES

struct __align__(8)  h4v { __half2 a, b; };          // 4 fp16 = 8 B
struct __align__(16) h8v { __half2 a, b, c, d; };    // 8 fp16 = 16 B (gather unit)

// ---------------- init: cnt/sums/gend/w2h/done (pk dropped — R10) ----------------

__global__ void k_init(int* __restrict__ cnt, float* __restrict__ sums,
                       const float* __restrict__ W2, __half* __restrict__ w2h,
                       const int* __restrict__ batch, int* __restrict__ gend,
                       int* __restrict__ done) {
    int i = blockIdx.x * 256 + threadIdx.x;
    if (i == 0) *done = 0;
    if (i < N_NODES) {
        cnt[i] = 0;
        // sorted batch: boundary -> this node ends its graph (all 64 graphs populated)
        if (i == N_NODES - 1 || batch[i] != batch[i + 1]) gend[batch[i]] = i + 1;
    }
    if (i < N_GRAPHS * 128) sums[i] = 0.f;
    if (i < 64 * 128) w2h[i] = __float2half_rn(W2[i]);
}

// ---------------- CSR build: ONE pass (fixed-stride rows), direct edge reads ----------------
// slot = atomicAdd(cnt[d]) doubles as degree count. XCD-partitioned:
// cnt lines and csr row destinations stay XCD-local. src read only when in-range (1/8).

__global__ void k_fill_direct(const int* __restrict__ src, const int* __restrict__ dst,
                              int* __restrict__ cnt, unsigned short* __restrict__ csr, int E) {
    const int range = blockIdx.x & 7;
    const int stripe = blockIdx.x >> 3;
    const int lo = range * (N_NODES / 8);
    const int hi = lo + (N_NODES / 8);
    for (int e = stripe * 256 + threadIdx.x; e < E; e += FILL_STRIPES * 256) {
        int d = dst[e];
        if (d >= lo && d < hi) {
            int slot = atomicAdd(&cnt[d], 1);
            if (slot < CAP) csr[(size_t)d * CAP + slot] = (unsigned short)src[e];
        }
    }
}

// ---------------- GEMM1: g̃(fp16) = dinv ⊙ (x @ W1) ----------------
// dinv computed on the fly from cnt (rsqrt of degree+1).

__global__ __launch_bounds__(256) void k_gemm1(const float* __restrict__ A,
                                               const float* __restrict__ W,
                                               const int* __restrict__ cnt,
                                               __half* __restrict__ Cout, int N) {
    const int FIN = 128;
    __shared__ __align__(16) float As[64 * (FIN + 2)];
    __shared__ __align__(16) float Wsm[FIN * 64];
    const int t = threadIdx.x;
    const int row0 = blockIdx.x * 64;

    const int NF4 = 64 * FIN / 4;
    for (int idx = t; idx < NF4; idx += 256) {
        int r = idx / (FIN / 4);
        int c4 = idx % (FIN / 4);
        float4 v = make_float4(0.f, 0.f, 0.f, 0.f);
        if (row0 + r < N) v = ((const float4*)(A + (size_t)(row0 + r) * FIN))[c4];
        float* p = &As[r * (FIN + 2) + c4 * 4];
        ((float2*)p)[0] = make_float2(v.x, v.y);
        ((float2*)p)[1] = make_float2(v.z, v.w);
    }
    for (int idx = t; idx < FIN * 16; idx += 256) {
        int r = idx / 16, c4 = idx % 16;
        *((float4*)&Wsm[r * 64 + c4 * 4]) = ((const float4*)(W + (size_t)r * 64))[c4];
    }
    __syncthreads();

    const int tc = (t & 15) * 4;
    const int tr = (t >> 4) * 4;
    float acc[4][4] = {};
#pragma unroll 4
    for (int k = 0; k < FIN; k += 2) {
        float2 a[4];
#pragma unroll
        for (int r = 0; r < 4; ++r)
            a[r] = *(const float2*)&As[(tr + r) * (FIN + 2) + k];
        float4 w0 = *(const float4*)&Wsm[k * 64 + tc];
        float4 w1 = *(const float4*)&Wsm[(k + 1) * 64 + tc];
#pragma unroll
        for (int r = 0; r < 4; ++r) {
            acc[r][0] = fmaf(a[r].x, w0.x, acc[r][0]);
            acc[r][1] = fmaf(a[r].x, w0.y, acc[r][1]);
            acc[r][2] = fmaf(a[r].x, w0.z, acc[r][2]);
            acc[r][3] = fmaf(a[r].x, w0.w, acc[r][3]);
            acc[r][0] = fmaf(a[r].y, w1.x, acc[r][0]);
            acc[r][1] = fmaf(a[r].y, w1.y, acc[r][1]);
            acc[r][2] = fmaf(a[r].y, w1.z, acc[r][2]);
            acc[r][3] = fmaf(a[r].y, w1.w, acc[r][3]);
        }
    }

#pragma unroll
    for (int r = 0; r < 4; ++r) {
        int row = row0 + tr + r;
        if (row < N) {
            float s = rsqrtf((float)(min(cnt[row], CAP) + 1));
            __half2* dsth = (__half2*)(Cout + (size_t)row * 64 + tc);
            dsth[0] = __floats2half2_rn(acc[r][0] * s, acc[r][1] * s);
            dsth[1] = __floats2half2_rn(acc[r][2] * s, acc[r][3] * s);
        }
    }
}

// ---------------- aggregates: 8 lanes/node, 16 B/lane (dwordx4), 0 LDS ----------------
// R8-verified shape. NOTE (R9 lesson, rule #20): accumulators MUST be named
// scalars — a float[8] passed by pointer goes to scratch (5x slowdown, VGPR=64).

template <bool RELU>
__global__ void k_agg(const h8v* __restrict__ h, const int* __restrict__ cnt,
                      const unsigned short* __restrict__ csr,
                      const float* __restrict__ bias, h8v* __restrict__ out, int N) {
    int node = blockIdx.x * 32 + (threadIdx.x >> 3);
    int lane = threadIdx.x & 7;
    if (node >= N) return;
    int c = min(cnt[node], CAP);
    float di = rsqrtf((float)(c + 1));
    h8v sv = h[(size_t)node * 8 + lane];  // self loop (pre-scaled)
    float2 p0 = __half22float2(sv.a), p1 = __half22float2(sv.b);
    float2 p2 = __half22float2(sv.c), p3 = __half22float2(sv.d);
    float f0 = p0.x, f1 = p0.y, f2 = p1.x, f3 = p1.y;
    float f4 = p2.x, f5 = p2.y, f6 = p3.x, f7 = p3.y;
    float g0 = 0, g1 = 0, g2 = 0, g3 = 0, g4 = 0, g5 = 0, g6 = 0, g7 = 0;
    const unsigned short* row = csr + (size_t)node * CAP;
    int j = 0;
    for (; j + 4 <= c; j += 4) {
        ushort4 s4 = *(const ushort4*)(row + j);   // 8B, broadcast across the 8 lanes
        h8v v0 = h[(size_t)s4.x * 8 + lane];
        h8v v1 = h[(size_t)s4.y * 8 + lane];
        h8v v2 = h[(size_t)s4.z * 8 + lane];
        h8v v3 = h[(size_t)s4.w * 8 + lane];
        float2 a0 = __half22float2(v0.a), a1 = __half22float2(v0.b),
               a2 = __half22float2(v0.c), a3 = __half22float2(v0.d);
        float2 b0 = __half22float2(v1.a), b1 = __half22float2(v1.b),
               b2 = __half22float2(v1.c), b3 = __half22float2(v1.d);
        f0 += a0.x; f1 += a0.y; f2 += a1.x; f3 += a1.y;
        f4 += a2.x; f5 += a2.y; f6 += a3.x; f7 += a3.y;
        g0 += b0.x; g1 += b0.y; g2 += b1.x; g3 += b1.y;
        g4 += b2.x; g5 += b2.y; g6 += b3.x; g7 += b3.y;
        float2 c0 = __half22float2(v2.a), c1 = __half22float2(v2.b),
               c2 = __half22float2(v2.c), c3 = __half22float2(v2.d);
        float2 d0 = __half22float2(v3.a), d1 = __half22float2(v3.b),
               d2 = __half22float2(v3.c), d3 = __half22float2(v3.d);
        f0 += c0.x; f1 += c0.y; f2 += c1.x; f3 += c1.y;
        f4 += c2.x; f5 += c2.y; f6 += c3.x; f7 += c3.y;
        g0 += d0.x; g1 += d0.y; g2 += d1.x; g3 += d1.y;
        g4 += d2.x; g5 += d2.y; g6 += d3.x; g7 += d3.y;
    }
    for (; j < c; ++j) {
        h8v v = h[(size_t)row[j] * 8 + lane];
        float2 a0 = __half22float2(v.a), a1 = __half22float2(v.b),
               a2 = __half22float2(v.c), a3 = __half22float2(v.d);
        f0 += a0.x; f1 += a0.y; f2 += a1.x; f3 += a1.y;
        f4 += a2.x; f5 += a2.y; f6 += a3.x; f7 += a3.y;
    }
    float s0 = f0 + g0, s1 = f1 + g1, s2 = f2 + g2, s3 = f3 + g3;
    float s4 = f4 + g4, s5 = f5 + g5, s6 = f6 + g6, s7 = f7 + g7;
    h8v o;
    if (RELU) {
        float4 bv0 = ((const float4*)bias)[lane * 2];
        float4 bv1 = ((const float4*)bias)[lane * 2 + 1];
        float r0 = fmaf(s0, di, bv0.x); r0 = r0 > 0.f ? r0 : 0.f;
        float r1 = fmaf(s1, di, bv0.y); r1 = r1 > 0.f ? r1 : 0.f;
        float r2 = fmaf(s2, di, bv0.z); r2 = r2 > 0.f ? r2 : 0.f;
        float r3 = fmaf(s3, di, bv0.w); r3 = r3 > 0.f ? r3 : 0.f;
        float r4 = fmaf(s4, di, bv1.x); r4 = r4 > 0.f ? r4 : 0.f;
        float r5 = fmaf(s5, di, bv1.y); r5 = r5 > 0.f ? r5 : 0.f;
        float r6 = fmaf(s6, di, bv1.z); r6 = r6 > 0.f ? r6 : 0.f;
        float r7 = fmaf(s7, di, bv1.w); r7 = r7 > 0.f ? r7 : 0.f;
        o.a = __floats2half2_rn(di * r0, di * r1);
        o.b = __floats2half2_rn(di * r2, di * r3);
        o.c = __floats2half2_rn(di * r4, di * r5);
        o.d = __floats2half2_rn(di * r6, di * r7);
    } else {
        o.a = __floats2half2_rn(s0 * di, s1 * di);
        o.b = __floats2half2_rn(s2 * di, s3 * di);
        o.c = __floats2half2_rn(s4 * di, s5 * di);
        o.d = __floats2half2_rn(s6 * di, s7 * di);
    }
    out[(size_t)node * 8 + lane] = o;
}

// ---------------- GEMM2 + mean-pool + (last block) batched MLP ----------------
// Reads z̃ ONCE; W2 fp16 in LDS. After pooled atomics, done-counter ticket;
// the last block re-reads sums (atomic reads) and runs the 4-layer MLP as
// batched 64-row GEMMs across all 256 threads (~2 µs). Removes one dispatch.

__global__ __launch_bounds__(256) void k_gemm_pool128(
    const __half2* __restrict__ A2,    // z̃ [N][32] half2
    const __half2* __restrict__ w2h,   // [64][64] half2 = [64][128] halves
    const float* __restrict__ bias,    // b2[128]
    const int* __restrict__ batch,
    float* __restrict__ sums, int N,
    int* __restrict__ done, const int* __restrict__ gend,
    const float* __restrict__ M1, const float* __restrict__ c1,
    const float* __restrict__ M2, const float* __restrict__ c2,
    const float* __restrict__ M3, const float* __restrict__ c3,
    const float* __restrict__ M4, const float* __restrict__ c4,
    float* __restrict__ out) {
    // pooled LDS: As[64*66] f32 (16896B) + Wh[64*64] half2 (16384B) = 33280B.
    // MLP reuses it as G[64][128] f32 (32768B) / T-buffers.
    __shared__ __align__(16) unsigned char smem[33280];
    __shared__ float red[8][132];
    __shared__ int batchLDS[64];
    __shared__ bool amLast;
    float* As = (float*)smem;
    __half2* Wh = (__half2*)(smem + 16896);
    const int t = threadIdx.x;
    const int row0 = blockIdx.x * 64;

    for (int idx = t; idx < 4096; idx += 256) Wh[idx] = w2h[idx];
    if (t < 64) batchLDS[t] = batch[min(row0 + t, N - 1)];
    for (int idx = t; idx < 64 * 32; idx += 256) {
        int r = idx >> 5, c2 = idx & 31;
        float2 v = make_float2(0.f, 0.f);
        if (row0 + r < N) v = __half22float2(A2[(size_t)(row0 + r) * 32 + c2]);
        *(float2*)&As[r * 66 + c2 * 2] = v;
    }
    __syncthreads();

    const int tc = (t & 31) * 4;   // 0..124
    const int tr = (t >> 5) * 8;   // 0..56
    {
        float acc[8][4] = {};
#pragma unroll 4
        for (int k = 0; k < 64; k += 2) {
            float2 a[8];
#pragma unroll
            for (int r = 0; r < 8; ++r)
                a[r] = *(const float2*)&As[(tr + r) * 66 + k];
            h4v wv0 = *(const h4v*)&Wh[k * 64 + (tc >> 1)];
            h4v wv1 = *(const h4v*)&Wh[(k + 1) * 64 + (tc >> 1)];
            float2 w00 = __half22float2(wv0.a), w01 = __half22float2(wv0.b);
            float2 w10 = __half22float2(wv1.a), w11 = __half22float2(wv1.b);
#pragma unroll
            for (int r = 0; r < 8; ++r) {
                acc[r][0] = fmaf(a[r].x, w00.x, acc[r][0]);
                acc[r][1] = fmaf(a[r].x, w00.y, acc[r][1]);
                acc[r][2] = fmaf(a[r].x, w01.x, acc[r][2]);
                acc[r][3] = fmaf(a[r].x, w01.y, acc[r][3]);
                acc[r][0] = fmaf(a[r].y, w10.x, acc[r][0]);
                acc[r][1] = fmaf(a[r].y, w10.y, acc[r][1]);
                acc[r][2] = fmaf(a[r].y, w11.x, acc[r][2]);
                acc[r][3] = fmaf(a[r].y, w11.y, acc[r][3]);
            }
        }

        float4 bv = *(const float4*)&bias[tc];
        float v[8][4];
#pragma unroll
        for (int r = 0; r < 8; ++r) {
            bool valid = (row0 + tr + r) < N;
            v[r][0] = valid ? fmaxf(acc[r][0] + bv.x, 0.f) : 0.f;
            v[r][1] = valid ? fmaxf(acc[r][1] + bv.y, 0.f) : 0.f;
            v[r][2] = valid ? fmaxf(acc[r][2] + bv.z, 0.f) : 0.f;
            v[r][3] = valid ? fmaxf(acc[r][3] + bv.w, 0.f) : 0.f;
        }

        const int g0 = batchLDS[0], g1 = batchLDS[63];
        const int rg = t >> 5;
        for (int g = g0; g <= g1; ++g) {
            float p0 = 0.f, p1 = 0.f, p2 = 0.f, p3 = 0.f;
#pragma unroll
            for (int r = 0; r < 8; ++r) {
                if (batchLDS[tr + r] == g) { p0 += v[r][0]; p1 += v[r][1]; p2 += v[r][2]; p3 += v[r][3]; }
            }
            red[rg][tc + 0] = p0; red[rg][tc + 1] = p1;
            red[rg][tc + 2] = p2; red[rg][tc + 3] = p3;
            __syncthreads();
            for (int off = 4; off > 0; off >>= 1) {
                if (rg < off) {
#pragma unroll
                    for (int c = 0; c < 4; ++c) red[rg][tc + c] += red[rg + off][tc + c];
                }
                __syncthreads();
            }
            if (rg == 0) {
#pragma unroll
                for (int c = 0; c < 4; ++c)
                    atomicAdd(&sums[g * 128 + tc + c], red[0][tc + c]);
            }
            __syncthreads();
        }
    }

    // ---- ticket: last block runs the MLP ----
    __threadfence();
    __syncthreads();
    if (t == 0) amLast = (atomicAdd(done, 1) == (int)gridDim.x - 1);
    __syncthreads();
    if (!amLast) return;
    __threadfence();

    // ---- batched MLP: G[64][128] -> T1[64][64] -> T2 -> T3 -> out[64] ----
    float* G = (float*)smem;              // 32KB, overlays As+Wh (done with them)
    for (int idx = t; idx < N_GRAPHS * 128; idx += 256) {
        int g = idx >> 7;
        int lb = (g > 0) ? gend[g - 1] : 0;
        float cg = fmaxf((float)(gend[g] - lb), 1.0f);
        G[idx] = atomicAdd(&sums[idx], 0.f) / cg;   // atomic read: device-coherent
    }
    __syncthreads();

    const int mc = (t & 15) * 4;   // out col 0..60
    const int mr = (t >> 4) * 4;   // graph row 0..60
    float* T1 = (float*)smem;             // [64][64] (written after G fully read)
    float* T2 = (float*)(smem + 16384);   // [64][64]
    // layer 1: G[64][128] @ M1[128][64], leaky 0.2
    {
        float acc[4][4] = {};
        for (int k = 0; k < 128; ++k) {
            float4 w = *(const float4*)&M1[k * 64 + mc];
            float a0 = G[(mr + 0) * 128 + k], a1 = G[(mr + 1) * 128 + k];
            float a2 = G[(mr + 2) * 128 + k], a3 = G[(mr + 3) * 128 + k];
            acc[0][0] = fmaf(a0, w.x, acc[0][0]); acc[0][1] = fmaf(a0, w.y, acc[0][1]);
            acc[0][2] = fmaf(a0, w.z, acc[0][2]); acc[0][3] = fmaf(a0, w.w, acc[0][3]);
            acc[1][0] = fmaf(a1, w.x, acc[1][0]); acc[1][1] = fmaf(a1, w.y, acc[1][1]);
            acc[1][2] = fmaf(a1, w.z, acc[1][2]); acc[1][3] = fmaf(a1, w.w, acc[1][3]);
            acc[2][0] = fmaf(a2, w.x, acc[2][0]); acc[2][1] = fmaf(a2, w.y, acc[2][1]);
            acc[2][2] = fmaf(a2, w.z, acc[2][2]); acc[2][3] = fmaf(a2, w.w, acc[2][3]);
            acc[3][0] = fmaf(a3, w.x, acc[3][0]); acc[3][1] = fmaf(a3, w.y, acc[3][1]);
            acc[3][2] = fmaf(a3, w.z, acc[3][2]); acc[3][3] = fmaf(a3, w.w, acc[3][3]);
        }
        float4 cv = *(const float4*)&c1[mc];
        __syncthreads();   // all reads of G complete before T1 overwrite
#pragma unroll
        for (int r = 0; r < 4; ++r) {
            float o0 = acc[r][0] + cv.x, o1 = acc[r][1] + cv.y;
            float o2 = acc[r][2] + cv.z, o3 = acc[r][3] + cv.w;
            T1[(mr + r) * 64 + mc + 0] = o0 >= 0.f ? o0 : 0.2f * o0;
            T1[(mr + r) * 64 + mc + 1] = o1 >= 0.f ? o1 : 0.2f * o1;
            T1[(mr + r) * 64 + mc + 2] = o2 >= 0.f ? o2 : 0.2f * o2;
            T1[(mr + r) * 64 + mc + 3] = o3 >= 0.f ? o3 : 0.2f * o3;
        }
    }
    __syncthreads();
    // layer 2: T1 @ M2, leaky 0.1 -> T2
    {
        float acc[4][4] = {};
        for (int k = 0; k < 64; ++k) {
            float4 w = *(const float4*)&M2[k * 64 + mc];
            float a0 = T1[(mr + 0) * 64 + k], a1 = T1[(mr + 1) * 64 + k];
            float a2 = T1[(mr + 2) * 64 + k], a3 = T1[(mr + 3) * 64 + k];
            acc[0][0] = fmaf(a0, w.x, acc[0][0]); acc[0][1] = fmaf(a0, w.y, acc[0][1]);
            acc[0][2] = fmaf(a0, w.z, acc[0][2]); acc[0][3] = fmaf(a0, w.w, acc[0][3]);
            acc[1][0] = fmaf(a1, w.x, acc[1][0]); acc[1][1] = fmaf(a1, w.y, acc[1][1]);
            acc[1][2] = fmaf(a1, w.z, acc[1][2]); acc[1][3] = fmaf(a1, w.w, acc[1][3]);
            acc[2][0] = fmaf(a2, w.x, acc[2][0]); acc[2][1] = fmaf(a2, w.y, acc[2][1]);
            acc[2][2] = fmaf(a2, w.z, acc[2][2]); acc[2][3] = fmaf(a2, w.w, acc[2][3]);
            acc[3][0] = fmaf(a3, w.x, acc[3][0]); acc[3][1] = fmaf(a3, w.y, acc[3][1]);
            acc[3][2] = fmaf(a3, w.z, acc[3][2]); acc[3][3] = fmaf(a3, w.w, acc[3][3]);
        }
        float4 cv = *(const float4*)&c2[mc];
#pragma unroll
        for (int r = 0; r < 4; ++r) {
            float o0 = acc[r][0] + cv.x, o1 = acc[r][1] + cv.y;
            float o2 = acc[r][2] + cv.z, o3 = acc[r][3] + cv.w;
            T2[(mr + r) * 64 + mc + 0] = o0 >= 0.f ? o0 : 0.1f * o0;
            T2[(mr + r) * 64 + mc + 1] = o1 >= 0.f ? o1 : 0.1f * o1;
            T2[(mr + r) * 64 + mc + 2] = o2 >= 0.f ? o2 : 0.1f * o2;
            T2[(mr + r) * 64 + mc + 3] = o3 >= 0.f ? o3 : 0.1f * o3;
        }
    }
    __syncthreads();
    // layer 3: T2 @ M3, leaky 0.1 -> T1 (reuse)
    {
        float acc[4][4] = {};
        for (int k = 0; k < 64; ++k) {
            float4 w = *(const float4*)&M3[k * 64 + mc];
            float a0 = T2[(mr + 0) * 64 + k], a1 = T2[(mr + 1) * 64 + k];
            float a2 = T2[(mr + 2) * 64 + k], a3 = T2[(mr + 3) * 64 + k];
            acc[0][0] = fmaf(a0, w.x, acc[0][0]); acc[0][1] = fmaf(a0, w.y, acc[0][1]);
            acc[0][2] = fmaf(a0, w.z, acc[0][2]); acc[0][3] = fmaf(a0, w.w, acc[0][3]);
            acc[1][0] = fmaf(a1, w.x, acc[1][0]); acc[1][1] = fmaf(a1, w.y, acc[1][1]);
            acc[1][2] = fmaf(a1, w.z, acc[1][2]); acc[1][3] = fmaf(a1, w.w, acc[1][3]);
            acc[2][0] = fmaf(a2, w.x, acc[2][0]); acc[2][1] = fmaf(a2, w.y, acc[2][1]);
            acc[2][2] = fmaf(a2, w.z, acc[2][2]); acc[2][3] = fmaf(a2, w.w, acc[2][3]);
            acc[3][0] = fmaf(a3, w.x, acc[3][0]); acc[3][1] = fmaf(a3, w.y, acc[3][1]);
            acc[3][2] = fmaf(a3, w.z, acc[3][2]); acc[3][3] = fmaf(a3, w.w, acc[3][3]);
        }
        float4 cv = *(const float4*)&c3[mc];
        __syncthreads();   // guard T1 overwrite vs layer-2 readers
#pragma unroll
        for (int r = 0; r < 4; ++r) {
            float o0 = acc[r][0] + cv.x, o1 = acc[r][1] + cv.y;
            float o2 = acc[r][2] + cv.z, o3 = acc[r][3] + cv.w;
            T1[(mr + r) * 64 + mc + 0] = o0 >= 0.f ? o0 : 0.1f * o0;
            T1[(mr + r) * 64 + mc + 1] = o1 >= 0.f ? o1 : 0.1f * o1;
            T1[(mr + r) * 64 + mc + 2] = o2 >= 0.f ? o2 : 0.1f * o2;
            T1[(mr + r) * 64 + mc + 3] = o3 >= 0.f ? o3 : 0.1f * o3;
        }
    }
    __syncthreads();
    // layer 4: T1[64][64] @ M4[64] + c4, relu -> out[64]
    if (t < N_GRAPHS) {
        float acc = c4[0];
        for (int k = 0; k < 64; ++k) acc = fmaf(T1[t * 64 + k], M4[k], acc);
        out[t] = fmaxf(acc, 0.f);
    }
}

// ---------------- launch ----------------

extern "C" void kernel_launch(void* const* d_in, const int* in_sizes, int n_in,
                              void* d_out, int out_size, void* d_ws, size_t ws_size,
                              hipStream_t stream) {
    const float* x   = (const float*)d_in[0];
    const int*   ei  = (const int*)d_in[1];
    const int*   bat = (const int*)d_in[2];
    const float* W1  = (const float*)d_in[3];
    const float* b1  = (const float*)d_in[4];
    const float* W2  = (const float*)d_in[5];
    const float* b2  = (const float*)d_in[6];
    const float* M1  = (const float*)d_in[7];
    const float* c1  = (const float*)d_in[8];
    const float* M2  = (const float*)d_in[9];
    const float* c2  = (const float*)d_in[10];
    const float* M3  = (const float*)d_in[11];
    const float* c3  = (const float*)d_in[12];
    const float* M4  = (const float*)d_in[13];
    const float* c4  = (const float*)d_in[14];
    float* out = (float*)d_out;

    const int* src = ei;            // edge_index[0]
    const int* dst = ei + N_EDGES;  // edge_index[1]

    // workspace layout
    float* bufA    = (float*)d_ws;                          // g̃ / z̃: N*64 fp16
    float* bufB    = bufA + (size_t)N_NODES * 64;           // h̃1: N*64 fp16
    float* sums    = bufB + (size_t)N_NODES * 64;           // 64*128 f
    int*   cnt     = (int*)(sums + N_GRAPHS * 128);         // N i (degree/slot counter)
    unsigned short* csr = (unsigned short*)(cnt + N_NODES); // N*CAP u16 (fixed-stride rows)
    __half* w2h    = (__half*)(csr + (size_t)N_NODES * CAP);// 64*128 fp16
    int*   gend    = (int*)(w2h + 64 * 128);                // 64 i (graph end indices)
    int*   done    = gend + 64;                             // 1 i (ticket counter)

    // ---- init + one-pass CSR build (direct edge reads, pk dropped) ----
    k_init<<<(N_NODES + 255) / 256, 256, 0, stream>>>(cnt, sums, W2, w2h, bat, gend, done);
    k_fill_direct<<<8 * FILL_STRIPES, 256, 0, stream>>>(src, dst, cnt, csr, N_EDGES);

    const int NBLK = (N_NODES + 63) / 64;   // 782
    const int ABLK = (N_NODES + 31) / 32;   // 1563

    // ---- conv1: g̃(fp16) = dinv ⊙ (x@W1); h̃1(fp16) = dinv ⊙ relu(Â-sum + b1) ----
    k_gemm1<<<NBLK, 256, 0, stream>>>(x, W1, cnt, (__half*)bufA, N_NODES);
    k_agg<true><<<ABLK, 256, 0, stream>>>(
        (const h8v*)bufA, cnt, csr, b1, (h8v*)bufB, N_NODES);

    // ---- conv2: z̃ = dinv ⊙ (Σ h̃1); gemm2+relu+pool+MLP (last-block) ----
    k_agg<false><<<ABLK, 256, 0, stream>>>(
        (const h8v*)bufB, cnt, csr, nullptr, (h8v*)bufA, N_NODES);
    k_gemm_pool128<<<NBLK, 256, 0, stream>>>(
        (const __half2*)bufA, (const __half2*)w2h, b2, bat, sums, N_NODES,
        done, gend, M1, c1, M2, c2, M3, c3, M4, c4, out);
}

// Round 12
// 215.792 us; speedup vs baseline: 2.4134x; 1.3321x over previous
//
#include <hip/hip_runtime.h>
#include <hip/hip_fp16.h>

#define N_NODES 50000
#define N_EDGES 800000
#define N_GRAPHS 64

#define CAP 64            // fixed-stride CSR row capacity; P(deg>=64) ~ 1e-13 on Poisson(16)
#define FILL_STRIPES 256  // blocks per node-range; grid = 8*FILL_STRIPES

struct __align__(8)  h4v { __half2 a, b; };          // 4 fp16 = 8 B
struct __align__(16) h8v { __half2 a, b, c, d; };    // 8 fp16 = 16 B (gather unit)

// ---------------- init: cnt/sums/gend/w2h ----------------

__global__ void k_init(int* __restrict__ cnt, float* __restrict__ sums,
                       const float* __restrict__ W2, __half* __restrict__ w2h,
                       const int* __restrict__ batch, int* __restrict__ gend) {
    int i = blockIdx.x * 256 + threadIdx.x;
    if (i < N_NODES) {
        cnt[i] = 0;
        // sorted batch: boundary -> this node ends its graph (all 64 graphs populated)
        if (i == N_NODES - 1 || batch[i] != batch[i + 1]) gend[batch[i]] = i + 1;
    }
    if (i < N_GRAPHS * 128) sums[i] = 0.f;
    if (i < 64 * 128) w2h[i] = __float2half_rn(W2[i]);
}

// ---------------- CSR build: ONE pass (fixed-stride rows), direct edge reads ----------------
// slot = atomicAdd(cnt[d]) doubles as degree count. XCD-partitioned:
// cnt lines and csr row destinations stay XCD-local. src read only when in-range (1/8).

__global__ void k_fill_direct(const int* __restrict__ src, const int* __restrict__ dst,
                              int* __restrict__ cnt, unsigned short* __restrict__ csr, int E) {
    const int range = blockIdx.x & 7;
    const int stripe = blockIdx.x >> 3;
    const int lo = range * (N_NODES / 8);
    const int hi = lo + (N_NODES / 8);
    for (int e = stripe * 256 + threadIdx.x; e < E; e += FILL_STRIPES * 256) {
        int d = dst[e];
        if (d >= lo && d < hi) {
            int slot = atomicAdd(&cnt[d], 1);
            if (slot < CAP) csr[(size_t)d * CAP + slot] = (unsigned short)src[e];
        }
    }
}

// ---------------- GEMM1: g̃(fp16) = dinv ⊙ (x @ W1) ----------------
// dinv computed on the fly from cnt (rsqrt of degree+1).

__global__ __launch_bounds__(256) void k_gemm1(const float* __restrict__ A,
                                               const float* __restrict__ W,
                                               const int* __restrict__ cnt,
                                               __half* __restrict__ Cout, int N) {
    const int FIN = 128;
    __shared__ __align__(16) float As[64 * (FIN + 2)];
    __shared__ __align__(16) float Wsm[FIN * 64];
    const int t = threadIdx.x;
    const int row0 = blockIdx.x * 64;

    const int NF4 = 64 * FIN / 4;
    for (int idx = t; idx < NF4; idx += 256) {
        int r = idx / (FIN / 4);
        int c4 = idx % (FIN / 4);
        float4 v = make_float4(0.f, 0.f, 0.f, 0.f);
        if (row0 + r < N) v = ((const float4*)(A + (size_t)(row0 + r) * FIN))[c4];
        float* p = &As[r * (FIN + 2) + c4 * 4];
        ((float2*)p)[0] = make_float2(v.x, v.y);
        ((float2*)p)[1] = make_float2(v.z, v.w);
    }
    for (int idx = t; idx < FIN * 16; idx += 256) {
        int r = idx / 16, c4 = idx % 16;
        *((float4*)&Wsm[r * 64 + c4 * 4]) = ((const float4*)(W + (size_t)r * 64))[c4];
    }
    __syncthreads();

    const int tc = (t & 15) * 4;
    const int tr = (t >> 4) * 4;
    float acc[4][4] = {};
#pragma unroll 4
    for (int k = 0; k < FIN; k += 2) {
        float2 a[4];
#pragma unroll
        for (int r = 0; r < 4; ++r)
            a[r] = *(const float2*)&As[(tr + r) * (FIN + 2) + k];
        float4 w0 = *(const float4*)&Wsm[k * 64 + tc];
        float4 w1 = *(const float4*)&Wsm[(k + 1) * 64 + tc];
#pragma unroll
        for (int r = 0; r < 4; ++r) {
            acc[r][0] = fmaf(a[r].x, w0.x, acc[r][0]);
            acc[r][1] = fmaf(a[r].x, w0.y, acc[r][1]);
            acc[r][2] = fmaf(a[r].x, w0.z, acc[r][2]);
            acc[r][3] = fmaf(a[r].x, w0.w, acc[r][3]);
            acc[r][0] = fmaf(a[r].y, w1.x, acc[r][0]);
            acc[r][1] = fmaf(a[r].y, w1.y, acc[r][1]);
            acc[r][2] = fmaf(a[r].y, w1.z, acc[r][2]);
            acc[r][3] = fmaf(a[r].y, w1.w, acc[r][3]);
        }
    }

#pragma unroll
    for (int r = 0; r < 4; ++r) {
        int row = row0 + tr + r;
        if (row < N) {
            float s = rsqrtf((float)(min(cnt[row], CAP) + 1));
            __half2* dsth = (__half2*)(Cout + (size_t)row * 64 + tc);
            dsth[0] = __floats2half2_rn(acc[r][0] * s, acc[r][1] * s);
            dsth[1] = __floats2half2_rn(acc[r][2] * s, acc[r][3] * s);
        }
    }
}

// ---------------- aggregates: 8 lanes/node, 16 B/lane (dwordx4), 0 LDS ----------------
// R8-verified shape. NOTE (R9 lesson, rule #20): accumulators MUST be named
// scalars — a float[8] passed by pointer goes to scratch (5x slowdown).
// R11 lesson: keep gather at max occupancy and MLP on 64 blocks — fusing
// phases into low-parallelism tails costs ~10x more than a dispatch gap.

template <bool RELU>
__global__ void k_agg(const h8v* __restrict__ h, const int* __restrict__ cnt,
                      const unsigned short* __restrict__ csr,
                      const float* __restrict__ bias, h8v* __restrict__ out, int N) {
    int node = blockIdx.x * 32 + (threadIdx.x >> 3);
    int lane = threadIdx.x & 7;
    if (node >= N) return;
    int c = min(cnt[node], CAP);
    float di = rsqrtf((float)(c + 1));
    h8v sv = h[(size_t)node * 8 + lane];  // self loop (pre-scaled)
    float2 p0 = __half22float2(sv.a), p1 = __half22float2(sv.b);
    float2 p2 = __half22float2(sv.c), p3 = __half22float2(sv.d);
    float f0 = p0.x, f1 = p0.y, f2 = p1.x, f3 = p1.y;
    float f4 = p2.x, f5 = p2.y, f6 = p3.x, f7 = p3.y;
    float g0 = 0, g1 = 0, g2 = 0, g3 = 0, g4 = 0, g5 = 0, g6 = 0, g7 = 0;
    const unsigned short* row = csr + (size_t)node * CAP;
    int j = 0;
    for (; j + 4 <= c; j += 4) {
        ushort4 s4 = *(const ushort4*)(row + j);   // 8B, broadcast across the 8 lanes
        h8v v0 = h[(size_t)s4.x * 8 + lane];
        h8v v1 = h[(size_t)s4.y * 8 + lane];
        h8v v2 = h[(size_t)s4.z * 8 + lane];
        h8v v3 = h[(size_t)s4.w * 8 + lane];
        float2 a0 = __half22float2(v0.a), a1 = __half22float2(v0.b),
               a2 = __half22float2(v0.c), a3 = __half22float2(v0.d);
        float2 b0 = __half22float2(v1.a), b1 = __half22float2(v1.b),
               b2 = __half22float2(v1.c), b3 = __half22float2(v1.d);
        f0 += a0.x; f1 += a0.y; f2 += a1.x; f3 += a1.y;
        f4 += a2.x; f5 += a2.y; f6 += a3.x; f7 += a3.y;
        g0 += b0.x; g1 += b0.y; g2 += b1.x; g3 += b1.y;
        g4 += b2.x; g5 += b2.y; g6 += b3.x; g7 += b3.y;
        float2 c0 = __half22float2(v2.a), c1 = __half22float2(v2.b),
               c2 = __half22float2(v2.c), c3 = __half22float2(v2.d);
        float2 d0 = __half22float2(v3.a), d1 = __half22float2(v3.b),
               d2 = __half22float2(v3.c), d3 = __half22float2(v3.d);
        f0 += c0.x; f1 += c0.y; f2 += c1.x; f3 += c1.y;
        f4 += c2.x; f5 += c2.y; f6 += c3.x; f7 += c3.y;
        g0 += d0.x; g1 += d0.y; g2 += d1.x; g3 += d1.y;
        g4 += d2.x; g5 += d2.y; g6 += d3.x; g7 += d3.y;
    }
    for (; j < c; ++j) {
        h8v v = h[(size_t)row[j] * 8 + lane];
        float2 a0 = __half22float2(v.a), a1 = __half22float2(v.b),
               a2 = __half22float2(v.c), a3 = __half22float2(v.d);
        f0 += a0.x; f1 += a0.y; f2 += a1.x; f3 += a1.y;
        f4 += a2.x; f5 += a2.y; f6 += a3.x; f7 += a3.y;
    }
    float s0 = f0 + g0, s1 = f1 + g1, s2 = f2 + g2, s3 = f3 + g3;
    float s4 = f4 + g4, s5 = f5 + g5, s6 = f6 + g6, s7 = f7 + g7;
    h8v o;
    if (RELU) {
        float4 bv0 = ((const float4*)bias)[lane * 2];
        float4 bv1 = ((const float4*)bias)[lane * 2 + 1];
        float r0 = fmaf(s0, di, bv0.x); r0 = r0 > 0.f ? r0 : 0.f;
        float r1 = fmaf(s1, di, bv0.y); r1 = r1 > 0.f ? r1 : 0.f;
        float r2 = fmaf(s2, di, bv0.z); r2 = r2 > 0.f ? r2 : 0.f;
        float r3 = fmaf(s3, di, bv0.w); r3 = r3 > 0.f ? r3 : 0.f;
        float r4 = fmaf(s4, di, bv1.x); r4 = r4 > 0.f ? r4 : 0.f;
        float r5 = fmaf(s5, di, bv1.y); r5 = r5 > 0.f ? r5 : 0.f;
        float r6 = fmaf(s6, di, bv1.z); r6 = r6 > 0.f ? r6 : 0.f;
        float r7 = fmaf(s7, di, bv1.w); r7 = r7 > 0.f ? r7 : 0.f;
        o.a = __floats2half2_rn(di * r0, di * r1);
        o.b = __floats2half2_rn(di * r2, di * r3);
        o.c = __floats2half2_rn(di * r4, di * r5);
        o.d = __floats2half2_rn(di * r6, di * r7);
    } else {
        o.a = __floats2half2_rn(s0 * di, s1 * di);
        o.b = __floats2half2_rn(s2 * di, s3 * di);
        o.c = __floats2half2_rn(s4 * di, s5 * di);
        o.d = __floats2half2_rn(s6 * di, s7 * di);
    }
    out[(size_t)node * 8 + lane] = o;
}

// ---------------- GEMM2 + mean-pool, single pass over full 128 cols ----------------
// Reads z̃ ONCE; W2 fp16 in LDS (16KB) makes the full-width tile fit.
// R11 lesson: NO fused MLP tail — single-block epilogue cost ~95 µs.

__global__ __launch_bounds__(256) void k_gemm_pool128(
    const __half2* __restrict__ A2,    // z̃ [N][32] half2
    const __half2* __restrict__ w2h,   // [64][64] half2 = [64][128] halves
    const float* __restrict__ bias,    // b2[128]
    const int* __restrict__ batch,
    float* __restrict__ sums, int N) {
    __shared__ __align__(16) float As[64 * 66];
    __shared__ __align__(16) __half2 Wh[64 * 64];   // 16 KB
    __shared__ float red[8][132];
    __shared__ int batchLDS[64];
    const int t = threadIdx.x;
    const int row0 = blockIdx.x * 64;

    for (int idx = t; idx < 4096; idx += 256) Wh[idx] = w2h[idx];
    if (t < 64) batchLDS[t] = batch[min(row0 + t, N - 1)];
    for (int idx = t; idx < 64 * 32; idx += 256) {
        int r = idx >> 5, c2 = idx & 31;
        float2 v = make_float2(0.f, 0.f);
        if (row0 + r < N) v = __half22float2(A2[(size_t)(row0 + r) * 32 + c2]);
        *(float2*)&As[r * 66 + c2 * 2] = v;
    }
    __syncthreads();

    const int tc = (t & 31) * 4;   // 0..124
    const int tr = (t >> 5) * 8;   // 0..56
    float acc[8][4] = {};
#pragma unroll 4
    for (int k = 0; k < 64; k += 2) {
        float2 a[8];
#pragma unroll
        for (int r = 0; r < 8; ++r)
            a[r] = *(const float2*)&As[(tr + r) * 66 + k];
        h4v wv0 = *(const h4v*)&Wh[k * 64 + (tc >> 1)];
        h4v wv1 = *(const h4v*)&Wh[(k + 1) * 64 + (tc >> 1)];
        float2 w00 = __half22float2(wv0.a), w01 = __half22float2(wv0.b);
        float2 w10 = __half22float2(wv1.a), w11 = __half22float2(wv1.b);
#pragma unroll
        for (int r = 0; r < 8; ++r) {
            acc[r][0] = fmaf(a[r].x, w00.x, acc[r][0]);
            acc[r][1] = fmaf(a[r].x, w00.y, acc[r][1]);
            acc[r][2] = fmaf(a[r].x, w01.x, acc[r][2]);
            acc[r][3] = fmaf(a[r].x, w01.y, acc[r][3]);
            acc[r][0] = fmaf(a[r].y, w10.x, acc[r][0]);
            acc[r][1] = fmaf(a[r].y, w10.y, acc[r][1]);
            acc[r][2] = fmaf(a[r].y, w11.x, acc[r][2]);
            acc[r][3] = fmaf(a[r].y, w11.y, acc[r][3]);
        }
    }

    float4 bv = *(const float4*)&bias[tc];
    float v[8][4];
#pragma unroll
    for (int r = 0; r < 8; ++r) {
        bool valid = (row0 + tr + r) < N;
        v[r][0] = valid ? fmaxf(acc[r][0] + bv.x, 0.f) : 0.f;
        v[r][1] = valid ? fmaxf(acc[r][1] + bv.y, 0.f) : 0.f;
        v[r][2] = valid ? fmaxf(acc[r][2] + bv.z, 0.f) : 0.f;
        v[r][3] = valid ? fmaxf(acc[r][3] + bv.w, 0.f) : 0.f;
    }

    const int g0 = batchLDS[0], g1 = batchLDS[63];
    const int rg = t >> 5;
    for (int g = g0; g <= g1; ++g) {
        float p0 = 0.f, p1 = 0.f, p2 = 0.f, p3 = 0.f;
#pragma unroll
        for (int r = 0; r < 8; ++r) {
            if (batchLDS[tr + r] == g) { p0 += v[r][0]; p1 += v[r][1]; p2 += v[r][2]; p3 += v[r][3]; }
        }
        red[rg][tc + 0] = p0; red[rg][tc + 1] = p1;
        red[rg][tc + 2] = p2; red[rg][tc + 3] = p3;
        __syncthreads();
        for (int off = 4; off > 0; off >>= 1) {
            if (rg < off) {
#pragma unroll
                for (int c = 0; c < 4; ++c) red[rg][tc + c] += red[rg + off][tc + c];
            }
            __syncthreads();
        }
        if (rg == 0) {
#pragma unroll
            for (int c = 0; c < 4; ++c)
                atomicAdd(&sums[g * 128 + tc + c], red[0][tc + c]);
        }
        __syncthreads();
    }
}

// ---------------- MLP head: one block per graph (counts precomputed) ----------------

__global__ void k_mlp(const float* __restrict__ sums, const int* __restrict__ gend,
                      const float* __restrict__ M1, const float* __restrict__ c1,
                      const float* __restrict__ M2, const float* __restrict__ c2,
                      const float* __restrict__ M3, const float* __restrict__ c3,
                      const float* __restrict__ M4, const float* __restrict__ c4,
                      float* __restrict__ out) {
    __shared__ float g[128], t1[64], t2[64], t3[64];
    __shared__ float cntb;
    int b = blockIdx.x;
    int t = threadIdx.x;
    if (t == 0) {
        int lb = (b > 0) ? gend[b - 1] : 0;
        cntb = fmaxf((float)(gend[b] - lb), 1.0f);
    }
    __syncthreads();
    if (t < 128) g[t] = sums[b * 128 + t] / cntb;
    __syncthreads();
    if (t < 64) {
        float acc = c1[t];
        for (int k = 0; k < 128; ++k) acc = fmaf(g[k], M1[k * 64 + t], acc);
        t1[t] = acc >= 0.f ? acc : 0.2f * acc;
    }
    __syncthreads();
    if (t < 64) {
        float acc = c2[t];
        for (int k = 0; k < 64; ++k) acc = fmaf(t1[k], M2[k * 64 + t], acc);
        t2[t] = acc >= 0.f ? acc : 0.1f * acc;
    }
    __syncthreads();
    if (t < 64) {
        float acc = c3[t];
        for (int k = 0; k < 64; ++k) acc = fmaf(t2[k], M3[k * 64 + t], acc);
        t3[t] = acc >= 0.f ? acc : 0.1f * acc;
    }
    __syncthreads();
    if (t == 0) {
        float acc = c4[0];
        for (int k = 0; k < 64; ++k) acc = fmaf(t3[k], M4[k], acc);
        out[b] = fmaxf(acc, 0.f);
    }
}

// ---------------- launch ----------------

extern "C" void kernel_launch(void* const* d_in, const int* in_sizes, int n_in,
                              void* d_out, int out_size, void* d_ws, size_t ws_size,
                              hipStream_t stream) {
    const float* x   = (const float*)d_in[0];
    const int*   ei  = (const int*)d_in[1];
    const int*   bat = (const int*)d_in[2];
    const float* W1  = (const float*)d_in[3];
    const float* b1  = (const float*)d_in[4];
    const float* W2  = (const float*)d_in[5];
    const float* b2  = (const float*)d_in[6];
    const float* M1  = (const float*)d_in[7];
    const float* c1  = (const float*)d_in[8];
    const float* M2  = (const float*)d_in[9];
    const float* c2  = (const float*)d_in[10];
    const float* M3  = (const float*)d_in[11];
    const float* c3  = (const float*)d_in[12];
    const float* M4  = (const float*)d_in[13];
    const float* c4  = (const float*)d_in[14];
    float* out = (float*)d_out;

    const int* src = ei;            // edge_index[0]
    const int* dst = ei + N_EDGES;  // edge_index[1]

    // workspace layout
    float* bufA    = (float*)d_ws;                          // g̃ / z̃: N*64 fp16
    float* bufB    = bufA + (size_t)N_NODES * 64;           // h̃1: N*64 fp16
    float* sums    = bufB + (size_t)N_NODES * 64;           // 64*128 f
    int*   cnt     = (int*)(sums + N_GRAPHS * 128);         // N i (degree/slot counter)
    unsigned short* csr = (unsigned short*)(cnt + N_NODES); // N*CAP u16 (fixed-stride rows)
    __half* w2h    = (__half*)(csr + (size_t)N_NODES * CAP);// 64*128 fp16
    int*   gend    = (int*)(w2h + 64 * 128);                // 64 i (graph end indices)

    // ---- init + one-pass CSR build (direct edge reads) ----
    k_init<<<(N_NODES + 255) / 256, 256, 0, stream>>>(cnt, sums, W2, w2h, bat, gend);
    k_fill_direct<<<8 * FILL_STRIPES, 256, 0, stream>>>(src, dst, cnt, csr, N_EDGES);

    const int NBLK = (N_NODES + 63) / 64;   // 782
    const int ABLK = (N_NODES + 31) / 32;   // 1563

    // ---- conv1: g̃(fp16) = dinv ⊙ (x@W1); h̃1(fp16) = dinv ⊙ relu(Â-sum + b1) ----
    k_gemm1<<<NBLK, 256, 0, stream>>>(x, W1, cnt, (__half*)bufA, N_NODES);
    k_agg<true><<<ABLK, 256, 0, stream>>>(
        (const h8v*)bufA, cnt, csr, b1, (h8v*)bufB, N_NODES);

    // ---- conv2: z̃ = dinv ⊙ (Σ h̃1); single-pass gemm2+relu+mean-pool ----
    k_agg<false><<<ABLK, 256, 0, stream>>>(
        (const h8v*)bufB, cnt, csr, nullptr, (h8v*)bufA, N_NODES);
    k_gemm_pool128<<<NBLK, 256, 0, stream>>>(
        (const __half2*)bufA, (const __half2*)w2h, b2, bat, sums, N_NODES);

    // ---- MLP ----
    k_mlp<<<N_GRAPHS, 128, 0, stream>>>(sums, gend,
                                        M1, c1, M2, c2, M3, c3, M4, c4, out);
}